// Round 8
// baseline (970.180 us; speedup 1.0000x reference)
//
#include <hip/hip_runtime.h>
#include <hip/hip_fp16.h>
#include <cstdint>
#include <cstddef>

#define BS 8
#define TT 256
#define DD 2048
#define NN 8192
#define KK 64
#define GG 512
#define GSZ 16
#define HH 64
#define MIN_ 69
#define MOUT_ 66
#define NSL 32     // slices per batch
#define SLN 256    // neurons per slice
#define NSENT 128  // sentinels per batch per parity (32 slices x 4 waves)

typedef float    f32x4 __attribute__((ext_vector_type(4)));
typedef uint32_t u32x4 __attribute__((ext_vector_type(4)));

// ---------------- Phase A: modulator (runs once) ----------------
// One WG per group g; w1/w2/b2 staged in LDS ONCE, all 8 batches looped
// inside (8x less weight traffic, 8x fewer WGs than R7 version).
__global__ __launch_bounds__(256) void modulator_kernel(
    const float* __restrict__ w1, const float* __restrict__ b1,
    const float* __restrict__ w2, const float* __restrict__ b2,
    const float* __restrict__ act0, const float* __restrict__ heb0,
    const float* __restrict__ dec0, const float* __restrict__ thr0,
    const float* __restrict__ nid,
    float* __restrict__ wconn, float* __restrict__ decayB, float* __restrict__ thrB)
{
  const int g = blockIdx.x, tid = threadIdx.x;
  __shared__ float w1s[MIN_ * HH];    // 4416 floats
  __shared__ float w2s[HH * MOUT_];   // 4224 floats
  __shared__ float b2s[MOUT_];
  __shared__ float xs[GSZ][MIN_];
  __shared__ float hd[GSZ * HH];

  for (int j = tid; j < MIN_ * HH; j += 256) w1s[j] = w1[(size_t)g * MIN_ * HH + j];
  for (int j = tid; j < HH * MOUT_; j += 256) w2s[j] = w2[(size_t)g * HH * MOUT_ + j];
  if (tid < MOUT_) b2s[tid] = b2[g * MOUT_ + tid];
  const float b1v = b1[g * HH + (tid & 63)];   // h = tid&63 is fixed per thread
  const int nbase = g * GSZ;

  for (int b = 0; b < BS; ++b) {
    __syncthreads();   // xs/hd free from previous batch
    // stage mod_in = [act(1), hebbian(64), decay(1), threshold(1), nid(2)]
    for (int j = tid; j < GSZ * KK; j += 256) {
      int s = j >> 6, k = j & 63;
      xs[s][1 + k] = heb0[((size_t)(b * NN + nbase + s)) * KK + k];
    }
    if (tid < GSZ) {
      int n = nbase + tid;
      xs[tid][0]  = act0[b * NN + n];
      xs[tid][65] = dec0[b * NN + n];
      xs[tid][66] = thr0[b * NN + n];
      xs[tid][67] = nid[2 * n];
      xs[tid][68] = nid[2 * n + 1];
    }
    __syncthreads();

    // hdn[s][h] = tanh(sum_i xs[s][i]*w1s[i][h] + b1[h])
    #pragma unroll
    for (int rep = 0; rep < 4; ++rep) {
      int s = rep * 4 + (tid >> 6), h = tid & 63;
      float acc = b1v;
      for (int i = 0; i < MIN_; ++i) acc = fmaf(xs[s][i], w1s[i * HH + h], acc);
      hd[s * HH + h] = tanhf(acc);
    }
    __syncthreads();

    // out[s][o] = sum_h hd[s][h]*w2s[h][o] + b2[o]
    for (int j = tid; j < GSZ * MOUT_; j += 256) {
      int s = j / MOUT_, o = j - s * MOUT_;
      float acc = b2s[o];
      for (int h = 0; h < HH; ++h) acc = fmaf(hd[s * HH + h], w2s[h * MOUT_ + o], acc);
      int gidx = b * NN + nbase + s;
      if (o < KK)       wconn[(size_t)gidx * KK + o] = acc;
      else if (o == KK) decayB[gidx] = 1.f / (1.f + expf(-acc));
      else              thrB[gidx]   = acc;
    }
  }
}

// ---------------- Phase B: 256-step recurrent scan ----------------
// 256 WGs (batch = blockIdx&7, slice = blockIdx>>3), 256 threads, 1 neuron/thread.
// Exchange payload: one dword per neuron = [tag=t+1 (hi16) | fp16 act (lo16)].
// Data IS the flag. R8: SENTINEL-HINTED poll — writers drop one dword per
// wave (sent = t+1, monotone) right after the data stores (no vmcnt: hint
// only); readers spin on the 128 sentinels (0.5KB/retry instead of 32KB),
// then reload once and verify the per-word tags (ground truth; exact-match).
// Rare stale-tag miss falls back to the reload-retry loop. Correctness and
// liveness rest ONLY on the tag check — identical induction to R6:
// writer publishes tag t+3 into pw only after its verified t+2 reload of
// pw^1; a peer stores t+2 only after completing its verified t+1 reload of
// pw => pw is never overwritten while still being polled for t+1.
__global__ __launch_bounds__(256, 1) void scan_kernel(
    const float* __restrict__ cc, const int* __restrict__ conn,
    const float* __restrict__ V0, const float* __restrict__ act0,
    const float* __restrict__ wconn, const float* __restrict__ decayB,
    const float* __restrict__ thrB,
    float* __restrict__ out, uint32_t* actbuf, uint32_t* sent)
{
  const int tid  = threadIdx.x;
  const int lane = tid & 63;
  const int wv   = tid >> 6;
  const int b   = blockIdx.x & 7;   // batch (XCD-grouped under round-robin)
  const int sl  = blockIdx.x >> 3;  // slice 0..31
  const int n    = sl * SLN + tid;
  const int gidx = b * NN + n;

  __shared__ float alds[NN];        // 32 KB: full act of batch b (fp32)

  // persistent per-thread state in registers: 64 weights + 64 byte-offsets
  f32x4 w4[16];
  int   ad[KK];
  {
    const f32x4* wr = reinterpret_cast<const f32x4*>(wconn + (size_t)gidx * KK);
    #pragma unroll
    for (int j = 0; j < 16; ++j) w4[j] = wr[j];
    const int4* ir = reinterpret_cast<const int4*>(conn + (size_t)n * KK);
    #pragma unroll
    for (int j = 0; j < KK / 4; ++j) {
      int4 v = ir[j];
      ad[4*j+0] = v.x << 2; ad[4*j+1] = v.y << 2;   // pre-scaled byte offsets
      ad[4*j+2] = v.z << 2; ad[4*j+3] = v.w << 2;
    }
  }
  float V     = V0[gidx];
  float dec   = decayB[gidx];
  float onemd = 1.f - dec;
  float thr   = thrB[gidx];

  // initial act into LDS (exact fp32)
  {
    const float4* src = reinterpret_cast<const float4*>(act0 + (size_t)b * NN);
    float4* dst = reinterpret_cast<float4*>(alds);
    #pragma unroll
    for (int j = 0; j < 8; ++j) dst[tid + j * 256] = src[tid + j * 256];
  }
  __syncthreads();

  float inj = cc[((size_t)b * TT) * DD + (n >> 2)];
  const char* abase = reinterpret_cast<const char*>(alds);

  for (int t = 0; t < TT; ++t) {
    // gather + dot over 64 random neighbors (LDS reads: act only)
    float s0 = 0.f, s1 = 0.f, s2 = 0.f, s3 = 0.f;
    #pragma unroll
    for (int j = 0; j < 16; ++j) {
      s0 = fmaf(*reinterpret_cast<const float*>(abase + ad[4*j+0]), w4[j].x, s0);
      s1 = fmaf(*reinterpret_cast<const float*>(abase + ad[4*j+1]), w4[j].y, s1);
      s2 = fmaf(*reinterpret_cast<const float*>(abase + ad[4*j+2]), w4[j].z, s2);
      s3 = fmaf(*reinterpret_cast<const float*>(abase + ad[4*j+3]), w4[j].w, s3);
    }
    float recv = (s0 + s1) + (s2 + s3) + inj;
    V = dec * V + onemd * recv;
    float x = V - thr;
    float a = 1.f / (1.f + expf(-x));

    const int pw = t & 1;

    if (t != TT - 1) {
      // publish [tag | fp16(a)] — data and flag in one dword, device-coherent
      uint32_t word = ((uint32_t)(t + 1) << 16) |
                      (uint32_t)__half_as_ushort(__float2half_rn(a));
      uint32_t* dst = actbuf + (size_t)pw * (BS * NN) + gidx;
      asm volatile("global_store_dword %0, %1, off sc0 sc1"
                   :: "v"(dst), "v"(word) : "memory");
      // sentinel hint (one per wave), issued right behind the data stores
      if (lane == 0) {
        uint32_t* sp = sent + (size_t)(pw * BS + b) * NSENT + sl * 4 + wv;
        uint32_t tv = (uint32_t)(t + 1);
        asm volatile("global_store_dword %0, %1, off sc0 sc1"
                     :: "v"(sp), "v"(tv) : "memory");
      }
    }

    // group-of-4 mean (fp32 path for output)
    float p = a + __shfl_xor(a, 1);
    p = p + __shfl_xor(p, 2);
    if ((tid & 3) == 0)
      out[((size_t)b * TT + t) * DD + sl * 64 + (tid >> 2)] = 0.25f * p;

    if (t == TT - 1) break;

    // hidden under the poll: next injection prefetch
    inj = cc[((size_t)b * TT + t + 1) * DD + (n >> 2)];

    // ---- cheap sentinel poll: 2 dword loads/lane per retry ----
    {
      const uint32_t tgt = (uint32_t)(t + 1);
      const uint32_t* sp = sent + (size_t)(pw * BS + b) * NSENT;
      for (;;) {
        uint32_t v0, v1;
        asm volatile("global_load_dword %0, %1, off sc0 sc1"
                     : "=v"(v0) : "v"(sp + lane));
        asm volatile("global_load_dword %0, %1, off sc0 sc1"
                     : "=v"(v1) : "v"(sp + 64 + lane));
        asm volatile("s_waitcnt vmcnt(0)" ::: "memory");
        if (__all(v0 >= tgt && v1 >= tgt)) break;
      }
    }

    // ---- single coherent reload + tag verify (fallback: retry) ----
    const uint32_t* src = actbuf + (size_t)pw * (BS * NN) + (size_t)b * NN;
    const uint32_t expect = (uint32_t)(t + 1) << 16;
    u32x4 vals[8];
    for (;;) {
      #pragma unroll
      for (int j = 0; j < 8; ++j) {
        const uint32_t* p4 = src + (tid << 2) + (j << 10);
        asm volatile("global_load_dwordx4 %0, %1, off sc0 sc1"
                     : "=v"(vals[j]) : "v"(p4));
      }
      asm volatile("s_waitcnt vmcnt(0)" ::: "memory");
      uint32_t bad = 0;
      #pragma unroll
      for (int j = 0; j < 8; ++j) {
        bad |= (vals[j].x & 0xFFFF0000u) ^ expect;
        bad |= (vals[j].y & 0xFFFF0000u) ^ expect;
        bad |= (vals[j].z & 0xFFFF0000u) ^ expect;
        bad |= (vals[j].w & 0xFFFF0000u) ^ expect;
      }
      if (bad == 0) break;
    }
    // unpack fp16 payloads into LDS as fp32
    {
      const int base = (tid << 2);
      #pragma unroll
      for (int j = 0; j < 8; ++j) {
        int o = base + (j << 10);
        alds[o + 0] = __half2float(__ushort_as_half((unsigned short)(vals[j].x & 0xFFFFu)));
        alds[o + 1] = __half2float(__ushort_as_half((unsigned short)(vals[j].y & 0xFFFFu)));
        alds[o + 2] = __half2float(__ushort_as_half((unsigned short)(vals[j].z & 0xFFFFu)));
        alds[o + 3] = __half2float(__ushort_as_half((unsigned short)(vals[j].w & 0xFFFFu)));
      }
    }
    __syncthreads();
  }
}

extern "C" void kernel_launch(void* const* d_in, const int* in_sizes, int n_in,
                              void* d_out, int out_size, void* d_ws, size_t ws_size,
                              hipStream_t stream)
{
  const float* cc   = (const float*)d_in[0];
  const float* w1   = (const float*)d_in[1];
  const float* b1   = (const float*)d_in[2];
  const float* w2   = (const float*)d_in[3];
  const float* b2   = (const float*)d_in[4];
  const int*   conn = (const int*)d_in[5];
  const float* nid  = (const float*)d_in[6];
  const float* V0   = (const float*)d_in[7];
  const float* act0 = (const float*)d_in[8];
  const float* heb0 = (const float*)d_in[9];
  const float* dec0 = (const float*)d_in[10];
  const float* thr0 = (const float*)d_in[11];
  float* out = (float*)d_out;

  char* ws = (char*)d_ws;
  float*    wconn  = (float*)ws;                               // 16 MB
  float*    decayB = (float*)(ws + (size_t)BS * NN * KK * 4);  // 8*8192
  float*    thrB   = decayB + BS * NN;                         // 8*8192
  uint32_t* actbuf = (uint32_t*)(thrB + BS * NN);              // 2*8*8192 dwords
  uint32_t* sent   = actbuf + 2 * BS * NN;                     // 2*8*128 dwords

  // zero tags + sentinels every launch (replay-deterministic)
  hipMemsetAsync(actbuf, 0, (2 * BS * NN + 2 * BS * NSENT) * sizeof(uint32_t), stream);

  modulator_kernel<<<dim3(GG), 256, 0, stream>>>(w1, b1, w2, b2, act0, heb0, dec0,
                                                 thr0, nid, wconn, decayB, thrB);
  scan_kernel<<<dim3(BS * NSL), 256, 0, stream>>>(cc, conn, V0, act0, wconn,
                                                  decayB, thrB, out, actbuf, sent);
}